// Round 2
// baseline (4966.026 us; speedup 1.0000x reference)
//
#include <hip/hip_runtime.h>

#define EPS_ 1e-5f
#define SCALE_ 0.03125f   // DIM^-0.5 = 1/32

__device__ __forceinline__ float bf2f(unsigned short s) {
  return __uint_as_float(((unsigned int)s) << 16);
}
__device__ __forceinline__ unsigned short f2bf(float f) {
  unsigned int u = __float_as_uint(f);
  unsigned int r = 0x7FFFu + ((u >> 16) & 1u);
  return (unsigned short)((u + r) >> 16);
}

// ---------- LN stats over C for x^T rows: mean/rstd per (b,l) ----------
__global__ __launch_bounds__(256) void ln_stats(const float* __restrict__ x,
                                                float* __restrict__ meanp,
                                                float* __restrict__ rstdp) {
  int tl = threadIdx.x & 63;
  int cg = threadIdx.x >> 6;             // 0..3
  int row = blockIdx.x * 64 + tl;        // b*4096 + l
  int bb = row >> 12, l = row & 4095;
  const float* xp = x + (long)bb * (1024L * 4096L) + l;
  float s = 0.f, s2 = 0.f;
  for (int c = cg; c < 1024; c += 4) {
    float v = xp[(long)c * 4096];
    s += v; s2 += v * v;
  }
  __shared__ float sh[2][4][64];
  sh[0][cg][tl] = s; sh[1][cg][tl] = s2;
  __syncthreads();
  if (threadIdx.x < 64) {
    float ts = sh[0][0][tl] + sh[0][1][tl] + sh[0][2][tl] + sh[0][3][tl];
    float t2 = sh[1][0][tl] + sh[1][1][tl] + sh[1][2][tl] + sh[1][3][tl];
    float mu = ts * (1.0f / 1024.0f);
    float var = t2 * (1.0f / 1024.0f) - mu * mu;
    meanp[row] = mu;
    rstdp[row] = rsqrtf(var + EPS_);
  }
}

// ---------- xn[b][l][c] = bf16(LN(x[b][c][l])) via LDS tile transpose ----------
__global__ __launch_bounds__(256) void xn_make(const float* __restrict__ x,
                                               unsigned short* __restrict__ xn,
                                               const float* __restrict__ meanp,
                                               const float* __restrict__ rstdp,
                                               const float* __restrict__ g,
                                               const float* __restrict__ beta) {
  __shared__ float tile[32][33];
  int b = blockIdx.z;
  int ct = blockIdx.y * 32;
  int lt = blockIdx.x * 32;
  int tx = threadIdx.x & 31, ty = threadIdx.x >> 5;  // ty 0..7
  const float* xp = x + (long)b * 4194304;
  int l = lt + tx;
  float mu = meanp[(b << 12) + l];
  float rs = rstdp[(b << 12) + l];
#pragma unroll
  for (int k = 0; k < 32; k += 8) {
    int c = ct + ty + k;
    float v = xp[(long)c * 4096 + l];
    tile[ty + k][tx] = (v - mu) * rs * g[c] + beta[c];
  }
  __syncthreads();
  unsigned short* xq = xn + (long)b * 4194304;
#pragma unroll
  for (int k = 0; k < 32; k += 8) {
    int ll = lt + ty + k;
    xq[(long)ll * 1024 + ct + tx] = f2bf(tile[tx][ty + k]);
  }
}

// ---------- generic fp32 transpose: dst[z][c][r] = src[z][r][c] ----------
__global__ __launch_bounds__(256) void transpose_f32(const float* __restrict__ src,
                                                     float* __restrict__ dst,
                                                     int R, int Cc, long sSrc, long sDst) {
  __shared__ float tile[32][33];
  int z = blockIdx.z;
  int rt = blockIdx.y * 32, ct = blockIdx.x * 32;
  int tx = threadIdx.x & 31, ty = threadIdx.x >> 5;
  const float* s = src + (long)z * sSrc;
  float* d = dst + (long)z * sDst;
#pragma unroll
  for (int k = 0; k < 32; k += 8) tile[ty + k][tx] = s[(long)(rt + ty + k) * Cc + ct + tx];
  __syncthreads();
#pragma unroll
  for (int k = 0; k < 32; k += 8) d[(long)(ct + ty + k) * R + rt + tx] = tile[tx][ty + k];
}

// ---------- generic 64x64x16 SGEMM, 256 thr, 4x4/thread ----------
enum { A_F32 = 0, A_BF16 = 1, A_T = 2 };   // A row-major f32 / row-major bf16 / K-major f32
enum { B_F32 = 0, B_BF16 = 1 };
enum { E_NONE = 0, E_SCALE = 1, E_UPD = 2, E_RELUB = 3, E_ADDB = 4 };

template <int AM, int BD, int EPI>
__global__ __launch_bounds__(256) void gemm_k(
    const void* __restrict__ Am, const void* __restrict__ Bm, float* __restrict__ Cf,
    int K, int lda, int ldb, int ldc, long sA, long sB, long sC,
    const float* __restrict__ bias, const float* __restrict__ colsum) {
  __shared__ float As[16][68];
  __shared__ float Bs[16][68];
  const int tid = threadIdx.x;
  const int z = blockIdx.z;
  const int bn = blockIdx.x * 64;
  const int bm = blockIdx.y * 64;
  const int ctn = tid & 15, ctm = tid >> 4;

  float acc[4][4] = {};

  const int a_m = tid >> 2;            // row-major A staging
  const int a_k = (tid & 3) << 2;
  const int t_m = (tid & 15) << 2;     // K-major staging (A_T and B)
  const int t_k = tid >> 4;            // 0..15

  for (int k0 = 0; k0 < K; k0 += 16) {
    if constexpr (AM == A_F32) {
      const float* Ap = (const float*)Am + (long)z * sA;
      float4 av = *(const float4*)&Ap[(long)(bm + a_m) * lda + (k0 + a_k)];
      As[a_k + 0][a_m] = av.x; As[a_k + 1][a_m] = av.y;
      As[a_k + 2][a_m] = av.z; As[a_k + 3][a_m] = av.w;
    } else if constexpr (AM == A_BF16) {
      const unsigned short* Ap = (const unsigned short*)Am + (long)z * sA;
      ushort4 av = *(const ushort4*)&Ap[(long)(bm + a_m) * lda + (k0 + a_k)];
      As[a_k + 0][a_m] = bf2f(av.x); As[a_k + 1][a_m] = bf2f(av.y);
      As[a_k + 2][a_m] = bf2f(av.z); As[a_k + 3][a_m] = bf2f(av.w);
    } else {  // A_T: A[k][m]
      const float* Ap = (const float*)Am + (long)z * sA;
      float4 av = *(const float4*)&Ap[(long)(k0 + t_k) * lda + (bm + t_m)];
      *(float4*)&As[t_k][t_m] = av;
    }
    if constexpr (BD == B_F32) {
      const float* Bp = (const float*)Bm + (long)z * sB;
      float4 bv = *(const float4*)&Bp[(long)(k0 + t_k) * ldb + (bn + t_m)];
      *(float4*)&Bs[t_k][t_m] = bv;
    } else {
      const unsigned short* Bp = (const unsigned short*)Bm + (long)z * sB;
      ushort4 bv = *(const ushort4*)&Bp[(long)(k0 + t_k) * ldb + (bn + t_m)];
      Bs[t_k][t_m + 0] = bf2f(bv.x); Bs[t_k][t_m + 1] = bf2f(bv.y);
      Bs[t_k][t_m + 2] = bf2f(bv.z); Bs[t_k][t_m + 3] = bf2f(bv.w);
    }
    __syncthreads();
#pragma unroll
    for (int kk = 0; kk < 16; ++kk) {
      float4 av = *(const float4*)&As[kk][ctm << 2];
      float4 bv = *(const float4*)&Bs[kk][ctn << 2];
      float a0[4] = {av.x, av.y, av.z, av.w};
      float b0[4] = {bv.x, bv.y, bv.z, bv.w};
#pragma unroll
      for (int i = 0; i < 4; ++i)
#pragma unroll
        for (int j = 0; j < 4; ++j) acc[i][j] = fmaf(a0[i], b0[j], acc[i][j]);
    }
    __syncthreads();
  }

  const int r0 = bm + (ctm << 2);
  const int c0 = bn + (ctn << 2);
  const long zoff = (long)z * sC;
#pragma unroll
  for (int i = 0; i < 4; ++i) {
    int r = r0 + i;
    long off = zoff + (long)r * ldc + c0;
    float cs_inv = 0.f;
    if constexpr (EPI == E_UPD) cs_inv = 1.0f / colsum[r];  // E_UPD only used with z==0
    float vals[4];
#pragma unroll
    for (int j = 0; j < 4; ++j) {
      float v = acc[i][j];
      if constexpr (EPI == E_SCALE) v *= SCALE_;
      else if constexpr (EPI == E_UPD) v = Cf[off + j] + v * cs_inv;
      else if constexpr (EPI == E_RELUB) { v += bias[c0 + j]; v = v > 0.f ? v : 0.f; }
      else if constexpr (EPI == E_ADDB) { v = Cf[off + j] + v + bias[c0 + j]; }
      vals[j] = v;
    }
    float4 o; o.x = vals[0]; o.y = vals[1]; o.z = vals[2]; o.w = vals[3];
    *(float4*)&Cf[off] = o;
  }
}

// ---------- row LN over D=1024, one block per row ----------
__global__ __launch_bounds__(256) void row_ln(const float* __restrict__ in,
                                              float* __restrict__ out,
                                              const float* __restrict__ g,
                                              const float* __restrict__ bvec) {
  long base = (long)blockIdx.x * 1024;
  int c = threadIdx.x << 2;
  float4 xv = *(const float4*)&in[base + c];
  float s = xv.x + xv.y + xv.z + xv.w;
  float s2 = xv.x * xv.x + xv.y * xv.y + xv.z * xv.z + xv.w * xv.w;
#pragma unroll
  for (int off = 32; off > 0; off >>= 1) {
    s += __shfl_down(s, off);
    s2 += __shfl_down(s2, off);
  }
  __shared__ float sh[8];
  if ((threadIdx.x & 63) == 0) {
    sh[threadIdx.x >> 6] = s;
    sh[4 + (threadIdx.x >> 6)] = s2;
  }
  __syncthreads();
  float ts = sh[0] + sh[1] + sh[2] + sh[3];
  float t2 = sh[4] + sh[5] + sh[6] + sh[7];
  float mu = ts * (1.0f / 1024.0f);
  float rs = rsqrtf(t2 * (1.0f / 1024.0f) - mu * mu + EPS_);
  float4 o;
  o.x = (xv.x - mu) * rs * g[c + 0] + bvec[c + 0];
  o.y = (xv.y - mu) * rs * g[c + 1] + bvec[c + 1];
  o.z = (xv.z - mu) * rs * g[c + 2] + bvec[c + 2];
  o.w = (xv.w - mu) * rs * g[c + 3] + bvec[c + 3];
  *(float4*)&out[base + c] = o;
}

// ---------- softmax over N=256 per row of attnT [B*L, 256], + 1e-8 ----------
__global__ __launch_bounds__(256) void softmax_rows(float* __restrict__ attnT) {
  int row = blockIdx.x * 4 + (threadIdx.x >> 6);
  int lane = threadIdx.x & 63;
  float* p = attnT + (long)row * 256 + (lane << 2);
  float4 v = *(const float4*)p;
  float m = fmaxf(fmaxf(v.x, v.y), fmaxf(v.z, v.w));
#pragma unroll
  for (int off = 32; off > 0; off >>= 1) m = fmaxf(m, __shfl_xor(m, off));
  float ex = expf(v.x - m), ey = expf(v.y - m), ez = expf(v.z - m), ew = expf(v.w - m);
  float s = ex + ey + ez + ew;
#pragma unroll
  for (int off = 32; off > 0; off >>= 1) s += __shfl_xor(s, off);
  float inv = 1.0f / s;
  v.x = ex * inv + 1e-8f; v.y = ey * inv + 1e-8f;
  v.z = ez * inv + 1e-8f; v.w = ew * inv + 1e-8f;
  *(float4*)p = v;
}

// ---------- colsum[b][n] = sum_l attnT[b][l][n], two stage ----------
__global__ __launch_bounds__(256) void colsum_partial(const float* __restrict__ attnT,
                                                      float* __restrict__ partial) {
  int b = blockIdx.x >> 4, chunk = blockIdx.x & 15;
  int n = threadIdx.x;
  const float* p = attnT + (long)b * 1048576 + (long)chunk * 65536 + n;
  float s = 0.f;
  for (int l = 0; l < 256; ++l) s += p[l << 8];
  partial[blockIdx.x * 256 + n] = s;
}
__global__ __launch_bounds__(256) void colsum_reduce(const float* __restrict__ partial,
                                                     float* __restrict__ colsum) {
  int b = blockIdx.x, n = threadIdx.x;
  float s = 0.f;
#pragma unroll
  for (int c = 0; c < 16; ++c) s += partial[((b << 4) + c) * 256 + n];
  colsum[(b << 8) + n] = s;
}

// ---------- broadcast templates_init to [B,N,D] ----------
__global__ __launch_bounds__(256) void bcast_tmpl(const float* __restrict__ tinit,
                                                  float* __restrict__ tmpl) {
  long i = (long)blockIdx.x * 256 + threadIdx.x;
  tmpl[i] = tinit[i & 262143];
}

// ---------- final attn: dst[n][l] = src[l][n] / cs[n] (per batch) ----------
__global__ __launch_bounds__(256) void attn_final(const float* __restrict__ src,
                                                  float* __restrict__ dst,
                                                  const float* __restrict__ cs) {
  __shared__ float tile[32][33];
  int lt = blockIdx.x * 32, nt = blockIdx.y * 32;
  int tx = threadIdx.x & 31, ty = threadIdx.x >> 5;
#pragma unroll
  for (int k = 0; k < 32; k += 8) tile[ty + k][tx] = src[(long)(lt + ty + k) * 256 + nt + tx];
  __syncthreads();
#pragma unroll
  for (int k = 0; k < 32; k += 8) {
    int n = nt + ty + k;
    dst[(long)n * 4096 + lt + tx] = tile[tx][ty + k] / cs[n];
  }
}

extern "C" void kernel_launch(void* const* d_in, const int* in_sizes, int n_in,
                              void* d_out, int out_size, void* d_ws, size_t ws_size,
                              hipStream_t stream) {
  const float* x       = (const float*)d_in[0];
  const float* tinit   = (const float*)d_in[1];
  const float* Wq      = (const float*)d_in[2];
  const float* Wk      = (const float*)d_in[3];
  const float* Wv      = (const float*)d_in[4];
  const float* ln_in_g = (const float*)d_in[5];
  const float* ln_in_b = (const float*)d_in[6];
  const float* ln_t_g  = (const float*)d_in[7];
  const float* ln_t_b  = (const float*)d_in[8];
  const float* ln_m_g  = (const float*)d_in[9];
  const float* ln_m_b  = (const float*)d_in[10];
  const float* W1      = (const float*)d_in[11];
  const float* b1      = (const float*)d_in[12];
  const float* W2      = (const float*)d_in[13];
  const float* b2      = (const float*)d_in[14];
  (void)in_sizes; (void)n_in; (void)out_size; (void)ws_size;

  // ---- workspace layout (total ~92.3 MiB) ----
  char* ws = (char*)d_ws;
  size_t off = 0;
  auto alloc = [&](size_t bytes) {
    void* p = ws + off;
    off += (bytes + 255) & ~(size_t)255;
    return p;
  };
  float* meanp        = (float*)alloc(32768ULL * 4);
  float* rstdp        = (float*)alloc(32768ULL * 4);
  unsigned short* xn  = (unsigned short*)alloc(33554432ULL * 2);  // [B,L,C] bf16, 64MiB
  float* slabA        = (float*)alloc(2097152ULL * 4);  // tln / mfeat
  float* slabB        = (float*)alloc(2097152ULL * 4);  // qk / s / attn bounce
  float* slabC        = (float*)alloc(2097152ULL * 4);  // WkT / qkT / hidden / tmpl bounce
  float* Wqk          = (float*)alloc(1048576ULL * 4);  // scale*Wq*Wk^T
  float* partial      = (float*)alloc(32768ULL * 4);
  float* colsum       = (float*)alloc(2048ULL * 4);

  float* tmpl  = (float*)d_out;             // [B,N,D] during loop; transposed at end
  float* attnT = (float*)d_out + 2097152;   // [B,L,N] during loop; [B,N,L] at end

  float* tln    = slabA;
  float* mfeat  = slabA;
  float* qk     = slabB;
  float* s_buf  = slabB;
  float* WkT    = slabC;
  float* qkT    = slabC;
  float* hidden = slabC;

  dim3 blk(256);

  ln_stats<<<dim3(512), blk, 0, stream>>>(x, meanp, rstdp);
  xn_make<<<dim3(128, 32, 8), blk, 0, stream>>>(x, xn, meanp, rstdp, ln_in_g, ln_in_b);

  // Wqk = scale * Wq @ Wk^T  (precomputed once)
  transpose_f32<<<dim3(32, 32, 1), blk, 0, stream>>>(Wk, WkT, 1024, 1024, 0, 0);
  gemm_k<A_F32, B_F32, E_SCALE><<<dim3(16, 16, 1), blk, 0, stream>>>(
      Wq, WkT, Wqk, 1024, 1024, 1024, 1024, 0, 0, 0, nullptr, nullptr);

  bcast_tmpl<<<dim3(8192), blk, 0, stream>>>(tinit, tmpl);

  for (int it = 0; it < 6; ++it) {
    row_ln<<<dim3(2048), blk, 0, stream>>>(tmpl, tln, ln_t_g, ln_t_b);
    // qk = tln @ Wqk   [2048 x 1024]
    gemm_k<A_F32, B_F32, E_NONE><<<dim3(16, 32, 1), blk, 0, stream>>>(
        tln, Wqk, qk, 1024, 1024, 1024, 1024, 0, 0, 0, nullptr, nullptr);
    // qkT[b][c][n] = qk[b*256+n][c]
    transpose_f32<<<dim3(32, 8, 8), blk, 0, stream>>>(qk, qkT, 256, 1024, 262144, 262144);
    // attnT[b] = xn[b] (4096x1024 bf16) @ qkT[b] (1024x256)
    gemm_k<A_BF16, B_F32, E_NONE><<<dim3(4, 64, 8), blk, 0, stream>>>(
        xn, qkT, attnT, 1024, 1024, 256, 256, 4194304L, 262144L, 1048576L,
        nullptr, nullptr);
    softmax_rows<<<dim3(8192), blk, 0, stream>>>(attnT);
    colsum_partial<<<dim3(128), blk, 0, stream>>>(attnT, partial);
    colsum_reduce<<<dim3(8), blk, 0, stream>>>(partial, colsum);
    // s[b] = attnT[b]^T (256x4096) @ xn[b] (4096x1024)
    gemm_k<A_T, B_BF16, E_NONE><<<dim3(16, 4, 8), blk, 0, stream>>>(
        attnT, xn, s_buf, 4096, 256, 1024, 1024, 1048576L, 4194304L, 262144L,
        nullptr, nullptr);
    // tmpl += (s @ Wv) / colsum   [2048 x 1024]
    gemm_k<A_F32, B_F32, E_UPD><<<dim3(16, 32, 1), blk, 0, stream>>>(
        s_buf, Wv, tmpl, 1024, 1024, 1024, 1024, 0, 0, 0, nullptr, colsum);
    row_ln<<<dim3(2048), blk, 0, stream>>>(tmpl, mfeat, ln_m_g, ln_m_b);
    // hidden = relu(mfeat @ W1 + b1)   [2048 x 512]
    gemm_k<A_F32, B_F32, E_RELUB><<<dim3(8, 32, 1), blk, 0, stream>>>(
        mfeat, W1, hidden, 1024, 1024, 512, 512, 0, 0, 0, b1, nullptr);
    // tmpl += hidden @ W2 + b2   [2048 x 1024]
    gemm_k<A_F32, B_F32, E_ADDB><<<dim3(16, 32, 1), blk, 0, stream>>>(
        hidden, W2, tmpl, 512, 512, 1024, 1024, 0, 0, 0, b2, nullptr);
  }

  // out_templates: bounce tmpl through slabC, transpose [B,N,D] -> [B,D,N]
  hipMemcpyAsync(slabC, tmpl, 2097152ULL * 4, hipMemcpyDeviceToDevice, stream);
  transpose_f32<<<dim3(32, 8, 8), blk, 0, stream>>>(slabC, (float*)d_out, 256, 1024,
                                                    262144, 262144);
  // out_attn: per batch bounce attnT[b] through slabB, transpose + /colsum
  for (int b = 0; b < 8; ++b) {
    hipMemcpyAsync(slabB, attnT + (long)b * 1048576, 1048576ULL * 4,
                   hipMemcpyDeviceToDevice, stream);
    attn_final<<<dim3(128, 8), blk, 0, stream>>>(slabB, attnT + (long)b * 1048576,
                                                 colsum + b * 256);
  }
}

// Round 3
// 3516.339 us; speedup vs baseline: 1.4123x; 1.4123x over previous
//
#include <hip/hip_runtime.h>

#define EPS_ 1e-5f
#define SCALE_ 0.03125f   // DIM^-0.5 = 1/32

typedef __attribute__((ext_vector_type(8))) short short8;
typedef __attribute__((ext_vector_type(4))) float f32x4;
typedef unsigned short u16;

__device__ __forceinline__ float bf2f(u16 s) {
  return __uint_as_float(((unsigned int)s) << 16);
}
__device__ __forceinline__ u16 f2bf(float f) {
  unsigned int u = __float_as_uint(f);
  unsigned int r = 0x7FFFu + ((u >> 16) & 1u);
  return (u16)((u + r) >> 16);
}

// ---------- LN stats over C for x^T rows: mean/rstd per (b,l), all 8 b ----------
__global__ __launch_bounds__(256) void ln_stats(const float* __restrict__ x,
                                                float* __restrict__ meanp,
                                                float* __restrict__ rstdp) {
  int tl = threadIdx.x & 63;
  int cg = threadIdx.x >> 6;
  int row = blockIdx.x * 64 + tl;        // b*4096 + l
  int bb = row >> 12, l = row & 4095;
  const float* xp = x + (long)bb * (1024L * 4096L) + l;
  float s = 0.f, s2 = 0.f;
  for (int c = cg; c < 1024; c += 4) {
    float v = xp[(long)c * 4096];
    s += v; s2 += v * v;
  }
  __shared__ float sh[2][4][64];
  sh[0][cg][tl] = s; sh[1][cg][tl] = s2;
  __syncthreads();
  if (threadIdx.x < 64) {
    float ts = sh[0][0][tl] + sh[0][1][tl] + sh[0][2][tl] + sh[0][3][tl];
    float t2 = sh[1][0][tl] + sh[1][1][tl] + sh[1][2][tl] + sh[1][3][tl];
    float mu = ts * (1.0f / 1024.0f);
    float var = t2 * (1.0f / 1024.0f) - mu * mu;
    meanp[row] = mu;
    rstdp[row] = rsqrtf(var + EPS_);
  }
}

// ---------- xn[bl][l][c] = bf16(LN(x[bl][c][l])), per-group (z = local b) ----------
__global__ __launch_bounds__(256) void xn_make(const float* __restrict__ x,
                                               u16* __restrict__ xn,
                                               const float* __restrict__ meanp,
                                               const float* __restrict__ rstdp,
                                               const float* __restrict__ g,
                                               const float* __restrict__ beta) {
  __shared__ float tile[32][33];
  int b = blockIdx.z;
  int ct = blockIdx.y * 32;
  int lt = blockIdx.x * 32;
  int tx = threadIdx.x & 31, ty = threadIdx.x >> 5;
  const float* xp = x + (long)b * 4194304;
  int l = lt + tx;
  float mu = meanp[(b << 12) + l];
  float rs = rstdp[(b << 12) + l];
#pragma unroll
  for (int k = 0; k < 32; k += 8) {
    int c = ct + ty + k;
    float v = xp[(long)c * 4096 + l];
    tile[ty + k][tx] = (v - mu) * rs * g[c] + beta[c];
  }
  __syncthreads();
  u16* xq = xn + (long)b * 4194304;
#pragma unroll
  for (int k = 0; k < 32; k += 8) {
    int ll = lt + ty + k;
    xq[(long)ll * 1024 + ct + tx] = f2bf(tile[tx][ty + k]);
  }
}

// ---------- fp32 transpose (templates out): dst[z][c][r] = src[z][r][c] ----------
__global__ __launch_bounds__(256) void transpose_f32(const float* __restrict__ src,
                                                     float* __restrict__ dst,
                                                     int R, int Cc, long sSrc, long sDst) {
  __shared__ float tile[32][33];
  int z = blockIdx.z;
  int rt = blockIdx.y * 32, ct = blockIdx.x * 32;
  int tx = threadIdx.x & 31, ty = threadIdx.x >> 5;
  const float* s = src + (long)z * sSrc;
  float* d = dst + (long)z * sDst;
#pragma unroll
  for (int k = 0; k < 32; k += 8) tile[ty + k][tx] = s[(long)(rt + ty + k) * Cc + ct + tx];
  __syncthreads();
#pragma unroll
  for (int k = 0; k < 32; k += 8) d[(long)(ct + ty + k) * R + rt + tx] = tile[tx][ty + k];
}

// ---------- transpose + cast fp32 [R,C] -> bf16 [C,R] ----------
__global__ __launch_bounds__(256) void tcast(const float* __restrict__ src,
                                             u16* __restrict__ dst, int R, int C) {
  __shared__ float tile[32][33];
  int rt = blockIdx.y * 32, ct = blockIdx.x * 32;
  int tx = threadIdx.x & 31, ty = threadIdx.x >> 5;
#pragma unroll
  for (int k = 0; k < 32; k += 8) tile[ty + k][tx] = src[(long)(rt + ty + k) * C + ct + tx];
  __syncthreads();
#pragma unroll
  for (int k = 0; k < 32; k += 8) dst[(long)(ct + ty + k) * R + rt + tx] = f2bf(tile[tx][ty + k]);
}

// ---------- elementwise cast fp32 -> bf16 ----------
__global__ __launch_bounds__(256) void castbf(const float* __restrict__ in,
                                              u16* __restrict__ out) {
  long i = (long)blockIdx.x * 256 + threadIdx.x;
  out[i] = f2bf(in[i]);
}

// ---------- MFMA NT GEMM: C[m][n] = sum_k A[m][k]*Bt[n][k], bf16 in, fp32 acc ----
// BM=BN=128, BK=64, 256 thr (4 waves), wave tile 64x64 of 16x16x32 frags.
enum { E_BF16 = 0, E_SCALEBF = 1, E_F32 = 2, E_UPD = 3, E_RELU = 4, E_ADDB = 5 };

template <int EPI>
__global__ __launch_bounds__(256) void mgemm(
    const u16* __restrict__ A, const u16* __restrict__ Bt, void* __restrict__ Cv,
    int K, int lda, int ldb, int ldc, long sA, long sB, long sC,
    const float* __restrict__ bias, const float* __restrict__ colsum) {
  __shared__ u16 Als[128 * 64];
  __shared__ u16 Bls[128 * 64];
  const int tid = threadIdx.x;
  const int z = blockIdx.z;
  const int bm = blockIdx.y * 128;
  const int bn = blockIdx.x * 128;
  A += (long)z * sA;
  Bt += (long)z * sB;
  const int lane = tid & 63;
  const int w = tid >> 6;
  const int wm = (w & 1) * 64, wn = (w >> 1) * 64;
  const int fr = lane & 15;        // frag row/col within 16
  const int fq = lane >> 4;        // quad: k-offset group
  f32x4 acc[4][4] = {};

  for (int k0 = 0; k0 < K; k0 += 64) {
#pragma unroll
    for (int i = 0; i < 4; ++i) {
      int chunk = tid + i * 256;               // 0..1023
      int row = chunk >> 3, ko = (chunk & 7) << 3;
      short8 av = *(const short8*)&A[(long)(bm + row) * lda + k0 + ko];
      short8 bv = *(const short8*)&Bt[(long)(bn + row) * ldb + k0 + ko];
      *(short8*)&Als[chunk * 8] = av;
      *(short8*)&Bls[chunk * 8] = bv;
    }
    __syncthreads();
#pragma unroll
    for (int kc = 0; kc < 2; ++kc) {
      const int koff = kc * 32 + fq * 8;
      short8 af[4], bf[4];
#pragma unroll
      for (int i = 0; i < 4; ++i)
        af[i] = *(const short8*)&Als[(wm + i * 16 + fr) * 64 + koff];
#pragma unroll
      for (int j = 0; j < 4; ++j)
        bf[j] = *(const short8*)&Bls[(wn + j * 16 + fr) * 64 + koff];
#pragma unroll
      for (int i = 0; i < 4; ++i)
#pragma unroll
        for (int j = 0; j < 4; ++j)
          acc[i][j] = __builtin_amdgcn_mfma_f32_16x16x32_bf16(af[i], bf[j], acc[i][j], 0, 0, 0);
    }
    __syncthreads();
  }

  // C/D frag mapping (m89/m91-verified): col = lane&15, row = (lane>>4)*4 + r
#pragma unroll
  for (int i = 0; i < 4; ++i) {
#pragma unroll
    for (int j = 0; j < 4; ++j) {
      int gc = bn + wn + j * 16 + fr;
#pragma unroll
      for (int r = 0; r < 4; ++r) {
        int gr = bm + wm + i * 16 + fq * 4 + r;
        float v = acc[i][j][r];
        if constexpr (EPI == E_BF16) {
          ((u16*)Cv + (long)z * sC)[(long)gr * ldc + gc] = f2bf(v);
        } else if constexpr (EPI == E_SCALEBF) {
          ((u16*)Cv + (long)z * sC)[(long)gr * ldc + gc] = f2bf(v * SCALE_);
        } else if constexpr (EPI == E_F32) {
          ((float*)Cv + (long)z * sC)[(long)gr * ldc + gc] = v;
        } else if constexpr (EPI == E_UPD) {
          float* C = (float*)Cv + (long)z * sC;
          C[(long)gr * ldc + gc] += v * (1.0f / colsum[z * 256 + gr]);
        } else if constexpr (EPI == E_RELU) {
          float h = v + bias[gc];
          ((u16*)Cv + (long)z * sC)[(long)gr * ldc + gc] = f2bf(h > 0.f ? h : 0.f);
        } else {  // E_ADDB
          float* C = (float*)Cv + (long)z * sC;
          C[(long)gr * ldc + gc] += v + bias[gc];
        }
      }
    }
  }
}

// ---------- row LN over D=1024, fp32 in -> bf16 out ----------
__global__ __launch_bounds__(256) void row_ln_bf(const float* __restrict__ in,
                                                 u16* __restrict__ out,
                                                 const float* __restrict__ g,
                                                 const float* __restrict__ bvec) {
  long base = (long)blockIdx.x * 1024;
  int c = threadIdx.x << 2;
  float4 xv = *(const float4*)&in[base + c];
  float s = xv.x + xv.y + xv.z + xv.w;
  float s2 = xv.x * xv.x + xv.y * xv.y + xv.z * xv.z + xv.w * xv.w;
#pragma unroll
  for (int off = 32; off > 0; off >>= 1) {
    s += __shfl_down(s, off);
    s2 += __shfl_down(s2, off);
  }
  __shared__ float sh[8];
  if ((threadIdx.x & 63) == 0) {
    sh[threadIdx.x >> 6] = s;
    sh[4 + (threadIdx.x >> 6)] = s2;
  }
  __syncthreads();
  float ts = sh[0] + sh[1] + sh[2] + sh[3];
  float t2 = sh[4] + sh[5] + sh[6] + sh[7];
  float mu = ts * (1.0f / 1024.0f);
  float rs = rsqrtf(t2 * (1.0f / 1024.0f) - mu * mu + EPS_);
  ushort4 o;
  o.x = f2bf((xv.x - mu) * rs * g[c + 0] + bvec[c + 0]);
  o.y = f2bf((xv.y - mu) * rs * g[c + 1] + bvec[c + 1]);
  o.z = f2bf((xv.z - mu) * rs * g[c + 2] + bvec[c + 2]);
  o.w = f2bf((xv.w - mu) * rs * g[c + 3] + bvec[c + 3]);
  *(ushort4*)&out[base + c] = o;
}

// ---------- softmax over n (256) of logits[(bl*256+n)*4096 + l], -> bf16 attn ----
__global__ __launch_bounds__(256) void softmax_colg(const float* __restrict__ lg,
                                                    u16* __restrict__ attnbf) {
  int idx = blockIdx.x * 256 + threadIdx.x;   // 0..16383
  int bl = idx >> 12, l = idx & 4095;
  const float* p = lg + (long)bl * 1048576 + l;
  float mx = -1e30f;
  for (int n = 0; n < 256; ++n) mx = fmaxf(mx, p[(long)n << 12]);
  float s = 0.f;
  for (int n = 0; n < 256; ++n) s += __expf(p[(long)n << 12] - mx);
  float inv = 1.0f / s;
  u16* q = attnbf + (long)bl * 1048576 + l;
  for (int n = 0; n < 256; ++n)
    q[(long)n << 12] = f2bf(__expf(p[(long)n << 12] - mx) * inv + 1e-8f);
}

// ---------- colsum[row] = sum_l attnbf[row][l] (rows = bl*256+n) ----------
__global__ __launch_bounds__(256) void row_sum_bf(const u16* __restrict__ a,
                                                  float* __restrict__ colsum) {
  long base = (long)blockIdx.x * 4096 + threadIdx.x * 16;
  float s = 0.f;
#pragma unroll
  for (int i = 0; i < 16; i += 4) {
    ushort4 v = *(const ushort4*)&a[base + i];
    s += bf2f(v.x) + bf2f(v.y) + bf2f(v.z) + bf2f(v.w);
  }
#pragma unroll
  for (int off = 32; off > 0; off >>= 1) s += __shfl_down(s, off);
  __shared__ float sh[4];
  if ((threadIdx.x & 63) == 0) sh[threadIdx.x >> 6] = s;
  __syncthreads();
  if (threadIdx.x == 0) colsum[blockIdx.x] = sh[0] + sh[1] + sh[2] + sh[3];
}

// ---------- broadcast templates_init to group tmpl [4*256, 1024] ----------
__global__ __launch_bounds__(256) void bcast_tmpl(const float* __restrict__ tinit,
                                                  float* __restrict__ tmpl) {
  long i = (long)blockIdx.x * 256 + threadIdx.x;
  tmpl[i] = tinit[i & 262143];
}

// ---------- final attn: out fp32 = bf16 attn / colsum ----------
__global__ __launch_bounds__(256) void attn_final_g(const u16* __restrict__ ab,
                                                    const float* __restrict__ cs,
                                                    float* __restrict__ out) {
  long i = (long)blockIdx.x * 256 + threadIdx.x;  // < 4194304
  out[i] = bf2f(ab[i]) / cs[i >> 12];
}

extern "C" void kernel_launch(void* const* d_in, const int* in_sizes, int n_in,
                              void* d_out, int out_size, void* d_ws, size_t ws_size,
                              hipStream_t stream) {
  const float* x       = (const float*)d_in[0];
  const float* tinit   = (const float*)d_in[1];
  const float* Wq      = (const float*)d_in[2];
  const float* Wk      = (const float*)d_in[3];
  const float* Wv      = (const float*)d_in[4];
  const float* ln_in_g = (const float*)d_in[5];
  const float* ln_in_b = (const float*)d_in[6];
  const float* ln_t_g  = (const float*)d_in[7];
  const float* ln_t_b  = (const float*)d_in[8];
  const float* ln_m_g  = (const float*)d_in[9];
  const float* ln_m_b  = (const float*)d_in[10];
  const float* W1      = (const float*)d_in[11];
  const float* b1      = (const float*)d_in[12];
  const float* W2      = (const float*)d_in[13];
  const float* b2      = (const float*)d_in[14];
  (void)in_sizes; (void)n_in; (void)out_size; (void)ws_size;

  // ---- workspace (~87.3 MiB peak, proven-safe zone) ----
  char* ws = (char*)d_ws;
  size_t off = 0;
  auto alloc = [&](size_t bytes) {
    void* p = ws + off;
    off += (bytes + 255) & ~(size_t)255;
    return p;
  };
  float* meanp   = (float*)alloc(32768ULL * 4);
  float* rstdp   = (float*)alloc(32768ULL * 4);
  u16* xn        = (u16*)alloc(16777216ULL * 2);   // [4,4096,1024] bf16, 32 MB
  u16* vT        = (u16*)alloc(16777216ULL * 2);   // [4,1024,4096] bf16, 32 MB
  u16* attnbf    = (u16*)alloc(4194304ULL * 2);    // [4*256,4096] bf16, 8 MB
  u16* tln       = (u16*)alloc(1048576ULL * 2);    // tln / mfeat (aliased)
  u16* qk        = (u16*)alloc(1048576ULL * 2);
  u16* hidden    = (u16*)alloc(524288ULL * 2);
  float* tmpl    = (float*)alloc(1048576ULL * 4);  // [4*256,1024] fp32
  u16* WqkT      = (u16*)alloc(1048576ULL * 2);    // scale*Wk*Wq^T
  u16* WvT       = (u16*)alloc(1048576ULL * 2);
  u16* W1T       = (u16*)alloc(524288ULL * 2);
  u16* W2T       = (u16*)alloc(524288ULL * 2);
  float* colsum  = (float*)alloc(1024ULL * 4);

  // temp bf16 weight casts live in attnbf slab (dead until first softmax)
  u16* Wkbf = attnbf;
  u16* Wqbf = attnbf + 1048576;

  float* outT         = (float*)d_out;                 // [B,D,N]
  float* attnOutBase  = (float*)d_out + 2097152;       // [B,N,L] fp32 final
  float* logitsS      = attnOutBase + 4194304;         // 16 MB fp32 scratch (2nd half)

  dim3 blk(256);

  ln_stats<<<dim3(512), blk, 0, stream>>>(x, meanp, rstdp);

  // weight prep (once)
  castbf<<<dim3(4096), blk, 0, stream>>>(Wk, Wkbf);
  castbf<<<dim3(4096), blk, 0, stream>>>(Wq, Wqbf);
  // WqkT[c][dt] = scale * sum_d Wk[c][d]*Wq[dt][d]
  mgemm<E_SCALEBF><<<dim3(8, 8, 1), blk, 0, stream>>>(
      Wkbf, Wqbf, WqkT, 1024, 1024, 1024, 1024, 0, 0, 0, nullptr, nullptr);
  tcast<<<dim3(32, 32), blk, 0, stream>>>(Wv, WvT, 1024, 1024);   // [1024,1024] -> WvT
  tcast<<<dim3(16, 32), blk, 0, stream>>>(W1, W1T, 1024, 512);    // -> W1T [512,1024]
  tcast<<<dim3(32, 16), blk, 0, stream>>>(W2, W2T, 512, 1024);    // -> W2T [1024,512]

  for (int g = 0; g < 2; ++g) {
    const float* xg = x + (long)g * 16777216;
    float* mg = meanp + g * 16384;
    float* rg = rstdp + g * 16384;

    xn_make<<<dim3(128, 32, 4), blk, 0, stream>>>(xg, xn, mg, rg, ln_in_g, ln_in_b);
    // vT[z][d][l] = sum_c WvT[d][c] * xn[z][l][c]
    mgemm<E_BF16><<<dim3(32, 8, 4), blk, 0, stream>>>(
        WvT, xn, vT, 1024, 1024, 1024, 4096, 0, 4194304L, 4194304L, nullptr, nullptr);
    bcast_tmpl<<<dim3(4096), blk, 0, stream>>>(tinit, tmpl);

    for (int it = 0; it < 6; ++it) {
      row_ln_bf<<<dim3(1024), blk, 0, stream>>>(tmpl, tln, ln_t_g, ln_t_b);
      // qk[row][c] = sum_dt tln[row][dt] * WqkT[c][dt]
      mgemm<E_BF16><<<dim3(8, 8, 1), blk, 0, stream>>>(
          tln, WqkT, qk, 1024, 1024, 1024, 1024, 0, 0, 0, nullptr, nullptr);
      // logits[z][n][l] = sum_c qk[z*256+n][c] * xn[z][l][c]  (fp32 out)
      mgemm<E_F32><<<dim3(32, 2, 4), blk, 0, stream>>>(
          qk, xn, logitsS, 1024, 1024, 1024, 4096, 262144L, 4194304L, 1048576L,
          nullptr, nullptr);
      softmax_colg<<<dim3(64), blk, 0, stream>>>(logitsS, attnbf);
      row_sum_bf<<<dim3(1024), blk, 0, stream>>>(attnbf, colsum);
      // tmpl[z*256+n][d] += (sum_l attn[n][l]*vT[z][d][l]) / colsum
      mgemm<E_UPD><<<dim3(8, 2, 4), blk, 0, stream>>>(
          attnbf, vT, tmpl, 4096, 4096, 4096, 1024, 1048576L, 4194304L, 262144L,
          nullptr, colsum);
      row_ln_bf<<<dim3(1024), blk, 0, stream>>>(tmpl, tln, ln_m_g, ln_m_b);
      // hidden = relu(mfeat @ W1 + b1)
      mgemm<E_RELU><<<dim3(4, 8, 1), blk, 0, stream>>>(
          tln, W1T, hidden, 1024, 1024, 1024, 512, 0, 0, 0, b1, nullptr);
      // tmpl += hidden @ W2 + b2
      mgemm<E_ADDB><<<dim3(8, 8, 1), blk, 0, stream>>>(
          hidden, W2T, tmpl, 512, 512, 512, 1024, 0, 0, 0, b2, nullptr);
    }

    attn_final_g<<<dim3(16384), blk, 0, stream>>>(attnbf, colsum,
                                                  attnOutBase + (long)g * 4194304);
    transpose_f32<<<dim3(32, 8, 4), blk, 0, stream>>>(
        tmpl, outT + (long)g * 1048576, 256, 1024, 262144L, 262144L);
  }
}

// Round 4
// 2343.103 us; speedup vs baseline: 2.1194x; 1.5007x over previous
//
#include <hip/hip_runtime.h>

#define EPS_ 1e-5f
#define SCALE_ 0.03125f   // DIM^-0.5 = 1/32

typedef __attribute__((ext_vector_type(8))) short short8;
typedef __attribute__((ext_vector_type(4))) float f32x4;
typedef unsigned short u16;

__device__ __forceinline__ float bf2f(u16 s) {
  return __uint_as_float(((unsigned int)s) << 16);
}
__device__ __forceinline__ u16 f2bf(float f) {
  unsigned int u = __float_as_uint(f);
  unsigned int r = 0x7FFFu + ((u >> 16) & 1u);
  return (u16)((u + r) >> 16);
}

// ---------- LN stats stage 1: partial sums per (c-chunk, row) ----------
// grid 4096: lblk = bx>>3 (64 rows each), cchunk = bx&7 (128 c each)
__global__ __launch_bounds__(256) void ln_part(const float* __restrict__ x,
                                               float* __restrict__ ps,
                                               float* __restrict__ ps2) {
  int tl = threadIdx.x & 63;
  int cg = threadIdx.x >> 6;             // 0..3
  int lblk = blockIdx.x >> 3;
  int cchunk = blockIdx.x & 7;
  int row = lblk * 64 + tl;              // b*4096 + l
  int bb = row >> 12, l = row & 4095;
  const float* xp = x + (long)bb * 4194304L + l;
  int c0 = cchunk * 128 + cg;
  float s = 0.f, s2 = 0.f;
#pragma unroll
  for (int i = 0; i < 32; ++i) {
    float v = xp[(long)(c0 + i * 4) * 4096];
    s += v; s2 += v * v;
  }
  __shared__ float sh[2][4][64];
  sh[0][cg][tl] = s; sh[1][cg][tl] = s2;
  __syncthreads();
  if (threadIdx.x < 64) {
    float ts = sh[0][0][tl] + sh[0][1][tl] + sh[0][2][tl] + sh[0][3][tl];
    float t2 = sh[1][0][tl] + sh[1][1][tl] + sh[1][2][tl] + sh[1][3][tl];
    ps[cchunk * 32768 + row] = ts;
    ps2[cchunk * 32768 + row] = t2;
  }
}

// ---------- LN stats stage 2: reduce 8 chunks -> mean/rstd ----------
__global__ __launch_bounds__(256) void ln_red(const float* __restrict__ ps,
                                              const float* __restrict__ ps2,
                                              float* __restrict__ meanp,
                                              float* __restrict__ rstdp) {
  int row = blockIdx.x * 256 + threadIdx.x;
  float s = 0.f, s2 = 0.f;
#pragma unroll
  for (int k = 0; k < 8; ++k) {
    s += ps[k * 32768 + row];
    s2 += ps2[k * 32768 + row];
  }
  float mu = s * (1.0f / 1024.0f);
  float var = s2 * (1.0f / 1024.0f) - mu * mu;
  meanp[row] = mu;
  rstdp[row] = rsqrtf(var + EPS_);
}

// ---------- xn[z][l][c] = bf16(LN(x[z][c][l])) via LDS tile transpose ----------
__global__ __launch_bounds__(256) void xn_make(const float* __restrict__ x,
                                               u16* __restrict__ xn,
                                               const float* __restrict__ meanp,
                                               const float* __restrict__ rstdp,
                                               const float* __restrict__ g,
                                               const float* __restrict__ beta) {
  __shared__ float tile[32][33];
  int b = blockIdx.z;
  int ct = blockIdx.y * 32;
  int lt = blockIdx.x * 32;
  int tx = threadIdx.x & 31, ty = threadIdx.x >> 5;
  const float* xp = x + (long)b * 4194304;
  int l = lt + tx;
  float mu = meanp[(b << 12) + l];
  float rs = rstdp[(b << 12) + l];
#pragma unroll
  for (int k = 0; k < 32; k += 8) {
    int c = ct + ty + k;
    float v = xp[(long)c * 4096 + l];
    tile[ty + k][tx] = (v - mu) * rs * g[c] + beta[c];
  }
  __syncthreads();
  u16* xq = xn + (long)b * 4194304;
#pragma unroll
  for (int k = 0; k < 32; k += 8) {
    int ll = lt + ty + k;
    xq[(long)ll * 1024 + ct + tx] = f2bf(tile[tx][ty + k]);
  }
}

// ---------- fp32 transpose (templates out): dst[z][c][r] = src[z][r][c] ----------
__global__ __launch_bounds__(256) void transpose_f32(const float* __restrict__ src,
                                                     float* __restrict__ dst,
                                                     int R, int Cc, long sSrc, long sDst) {
  __shared__ float tile[32][33];
  int z = blockIdx.z;
  int rt = blockIdx.y * 32, ct = blockIdx.x * 32;
  int tx = threadIdx.x & 31, ty = threadIdx.x >> 5;
  const float* s = src + (long)z * sSrc;
  float* d = dst + (long)z * sDst;
#pragma unroll
  for (int k = 0; k < 32; k += 8) tile[ty + k][tx] = s[(long)(rt + ty + k) * Cc + ct + tx];
  __syncthreads();
#pragma unroll
  for (int k = 0; k < 32; k += 8) d[(long)(ct + ty + k) * R + rt + tx] = tile[tx][ty + k];
}

// ---------- transpose + cast fp32 [R,C] -> bf16 [C,R] ----------
__global__ __launch_bounds__(256) void tcast(const float* __restrict__ src,
                                             u16* __restrict__ dst, int R, int C) {
  __shared__ float tile[32][33];
  int rt = blockIdx.y * 32, ct = blockIdx.x * 32;
  int tx = threadIdx.x & 31, ty = threadIdx.x >> 5;
#pragma unroll
  for (int k = 0; k < 32; k += 8) tile[ty + k][tx] = src[(long)(rt + ty + k) * C + ct + tx];
  __syncthreads();
#pragma unroll
  for (int k = 0; k < 32; k += 8) dst[(long)(ct + ty + k) * R + rt + tx] = f2bf(tile[tx][ty + k]);
}

// ---------- elementwise cast fp32 -> bf16 ----------
__global__ __launch_bounds__(256) void castbf(const float* __restrict__ in,
                                              u16* __restrict__ out) {
  long i = (long)blockIdx.x * 256 + threadIdx.x;
  out[i] = f2bf(in[i]);
}

// ---------- MFMA NT GEMM: C[m][n] = sum_k A[m][k]*Bt[n][k], bf16 in, fp32 acc ----
// BM=BN=128, BK=64, 256 thr (4 waves), wave tile 64x64 of 16x16x32 frags.
// KSPLIT>1: blockIdx.z = zb*KSPLIT + ks; each ks covers K/KSPLIT; E_UPD -> atomicAdd.
enum { E_BF16 = 0, E_SCALEBF = 1, E_F32 = 2, E_UPD = 3, E_RELU = 4, E_ADDB = 5 };

template <int EPI, int KSPLIT = 1>
__global__ __launch_bounds__(256) void mgemm(
    const u16* __restrict__ A, const u16* __restrict__ Bt, void* __restrict__ Cv,
    int K, int lda, int ldb, int ldc, long sA, long sB, long sC,
    const float* __restrict__ bias, const float* __restrict__ colsum) {
  __shared__ u16 Als[128 * 64];
  __shared__ u16 Bls[128 * 64];
  const int tid = threadIdx.x;
  const int zb = (KSPLIT == 1) ? blockIdx.z : blockIdx.z / KSPLIT;
  const int ks = (KSPLIT == 1) ? 0 : blockIdx.z % KSPLIT;
  const int bm = blockIdx.y * 128;
  const int bn = blockIdx.x * 128;
  A += (long)zb * sA;
  Bt += (long)zb * sB;
  const int kpart = K / KSPLIT;
  const int kbase = ks * kpart;
  const int lane = tid & 63;
  const int w = tid >> 6;
  const int wm = (w & 1) * 64, wn = (w >> 1) * 64;
  const int fr = lane & 15;
  const int fq = lane >> 4;
  f32x4 acc[4][4] = {};

  for (int k0 = 0; k0 < kpart; k0 += 64) {
    const int kk = kbase + k0;
#pragma unroll
    for (int i = 0; i < 4; ++i) {
      int chunk = tid + i * 256;
      int row = chunk >> 3, ko = (chunk & 7) << 3;
      short8 av = *(const short8*)&A[(long)(bm + row) * lda + kk + ko];
      short8 bv = *(const short8*)&Bt[(long)(bn + row) * ldb + kk + ko];
      *(short8*)&Als[chunk * 8] = av;
      *(short8*)&Bls[chunk * 8] = bv;
    }
    __syncthreads();
#pragma unroll
    for (int kc = 0; kc < 2; ++kc) {
      const int koff = kc * 32 + fq * 8;
      short8 af[4], bf[4];
#pragma unroll
      for (int i = 0; i < 4; ++i)
        af[i] = *(const short8*)&Als[(wm + i * 16 + fr) * 64 + koff];
#pragma unroll
      for (int j = 0; j < 4; ++j)
        bf[j] = *(const short8*)&Bls[(wn + j * 16 + fr) * 64 + koff];
#pragma unroll
      for (int i = 0; i < 4; ++i)
#pragma unroll
        for (int j = 0; j < 4; ++j)
          acc[i][j] = __builtin_amdgcn_mfma_f32_16x16x32_bf16(af[i], bf[j], acc[i][j], 0, 0, 0);
    }
    __syncthreads();
  }

  // C/D frag mapping: col = lane&15, row = (lane>>4)*4 + r
#pragma unroll
  for (int i = 0; i < 4; ++i) {
#pragma unroll
    for (int j = 0; j < 4; ++j) {
      int gc = bn + wn + j * 16 + fr;
#pragma unroll
      for (int r = 0; r < 4; ++r) {
        int gr = bm + wm + i * 16 + fq * 4 + r;
        float v = acc[i][j][r];
        if constexpr (EPI == E_BF16) {
          ((u16*)Cv + (long)zb * sC)[(long)gr * ldc + gc] = f2bf(v);
        } else if constexpr (EPI == E_SCALEBF) {
          ((u16*)Cv + (long)zb * sC)[(long)gr * ldc + gc] = f2bf(v * SCALE_);
        } else if constexpr (EPI == E_F32) {
          ((float*)Cv + (long)zb * sC)[(long)gr * ldc + gc] = v;
        } else if constexpr (EPI == E_UPD) {
          float* C = (float*)Cv + (long)zb * sC;
          float add = v * (1.0f / colsum[zb * 256 + gr]);
          if constexpr (KSPLIT > 1) atomicAdd(&C[(long)gr * ldc + gc], add);
          else C[(long)gr * ldc + gc] += add;
        } else if constexpr (EPI == E_RELU) {
          float h = v + bias[gc];
          ((u16*)Cv + (long)zb * sC)[(long)gr * ldc + gc] = f2bf(h > 0.f ? h : 0.f);
        } else {  // E_ADDB
          float* C = (float*)Cv + (long)zb * sC;
          C[(long)gr * ldc + gc] += v + bias[gc];
        }
      }
    }
  }
}

// ---------- row LN over D=1024, fp32 in -> bf16 out ----------
__global__ __launch_bounds__(256) void row_ln_bf(const float* __restrict__ in,
                                                 u16* __restrict__ out,
                                                 const float* __restrict__ g,
                                                 const float* __restrict__ bvec) {
  long base = (long)blockIdx.x * 1024;
  int c = threadIdx.x << 2;
  float4 xv = *(const float4*)&in[base + c];
  float s = xv.x + xv.y + xv.z + xv.w;
  float s2 = xv.x * xv.x + xv.y * xv.y + xv.z * xv.z + xv.w * xv.w;
#pragma unroll
  for (int off = 32; off > 0; off >>= 1) {
    s += __shfl_down(s, off);
    s2 += __shfl_down(s2, off);
  }
  __shared__ float sh[8];
  if ((threadIdx.x & 63) == 0) {
    sh[threadIdx.x >> 6] = s;
    sh[4 + (threadIdx.x >> 6)] = s2;
  }
  __syncthreads();
  float ts = sh[0] + sh[1] + sh[2] + sh[3];
  float t2 = sh[4] + sh[5] + sh[6] + sh[7];
  float mu = ts * (1.0f / 1024.0f);
  float rs = rsqrtf(t2 * (1.0f / 1024.0f) - mu * mu + EPS_);
  ushort4 o;
  o.x = f2bf((xv.x - mu) * rs * g[c + 0] + bvec[c + 0]);
  o.y = f2bf((xv.y - mu) * rs * g[c + 1] + bvec[c + 1]);
  o.z = f2bf((xv.z - mu) * rs * g[c + 2] + bvec[c + 2]);
  o.w = f2bf((xv.w - mu) * rs * g[c + 3] + bvec[c + 3]);
  *(ushort4*)&out[base + c] = o;
}

// ---------- LDS-tiled softmax over n=256 for a 32-l tile, fp32 in -> bf16 out --
// grid (128 l-tiles, z). tile[n][l] stride 36 (16B-aligned rows, staggered banks)
__global__ __launch_bounds__(256) void softmax_tile(const float* __restrict__ lg,
                                                    u16* __restrict__ attnbf) {
  __shared__ float tile[256 * 36];
  __shared__ float pmax[8][32], psum[8][32];
  __shared__ float fm[32], fi[32];
  const int z = blockIdx.y;
  const int lt = blockIdx.x * 32;
  const int t = threadIdx.x;
  const float* base = lg + (long)z * 1048576 + lt;
  // load 256x32 tile: 8 passes x 32 rows, 8 threads/row (float4)
  const int lr = t >> 3, lcg = (t & 7) << 2;
#pragma unroll
  for (int p = 0; p < 8; ++p) {
    int n = p * 32 + lr;
    float4 v = *(const float4*)&base[(long)n * 4096 + lcg];
    *(float4*)&tile[n * 36 + lcg] = v;
  }
  __syncthreads();
  const int l = t & 31, g = t >> 5;  // group g handles n in [32g, 32g+32)
  // per-lane max over this group's 32 n
  float m = -1e30f;
#pragma unroll
  for (int i = 0; i < 32; ++i) m = fmaxf(m, tile[(g * 32 + i) * 36 + l]);
  pmax[g][l] = m;
  __syncthreads();
  if (t < 32) {
    float mm = pmax[0][t];
#pragma unroll
    for (int k = 1; k < 8; ++k) mm = fmaxf(mm, pmax[k][t]);
    fm[t] = mm;
  }
  __syncthreads();
  float mx = fm[l];
  float s = 0.f;
#pragma unroll
  for (int i = 0; i < 32; ++i) {
    int n = g * 32 + i;
    float e = __expf(tile[n * 36 + l] - mx);
    tile[n * 36 + l] = e;
    s += e;
  }
  psum[g][l] = s;
  __syncthreads();
  if (t < 32) {
    float ss = psum[0][t];
#pragma unroll
    for (int k = 1; k < 8; ++k) ss += psum[k][t];
    fi[t] = 1.0f / ss;
  }
  __syncthreads();
  float inv = fi[l];
  u16* outp = attnbf + (long)z * 1048576 + lt + l;
#pragma unroll
  for (int i = 0; i < 32; ++i) {
    int n = g * 32 + i;
    outp[(long)n * 4096] = f2bf(tile[n * 36 + l] * inv + 1e-8f);
  }
}

// ---------- colsum[row] = sum_l attnbf[row][l] (rows = z*256+n) ----------
__global__ __launch_bounds__(256) void row_sum_bf(const u16* __restrict__ a,
                                                  float* __restrict__ colsum) {
  long base = (long)blockIdx.x * 4096 + threadIdx.x * 16;
  float s = 0.f;
#pragma unroll
  for (int i = 0; i < 16; i += 4) {
    ushort4 v = *(const ushort4*)&a[base + i];
    s += bf2f(v.x) + bf2f(v.y) + bf2f(v.z) + bf2f(v.w);
  }
#pragma unroll
  for (int off = 32; off > 0; off >>= 1) s += __shfl_down(s, off);
  __shared__ float sh[4];
  if ((threadIdx.x & 63) == 0) sh[threadIdx.x >> 6] = s;
  __syncthreads();
  if (threadIdx.x == 0) colsum[blockIdx.x] = sh[0] + sh[1] + sh[2] + sh[3];
}

// ---------- broadcast templates_init to group tmpl [4*256, 1024] ----------
__global__ __launch_bounds__(256) void bcast_tmpl(const float* __restrict__ tinit,
                                                  float* __restrict__ tmpl) {
  long i = (long)blockIdx.x * 256 + threadIdx.x;
  tmpl[i] = tinit[i & 262143];
}

// ---------- final attn: out fp32 = bf16 attn / colsum ----------
__global__ __launch_bounds__(256) void attn_final_g(const u16* __restrict__ ab,
                                                    const float* __restrict__ cs,
                                                    float* __restrict__ out) {
  long i = (long)blockIdx.x * 256 + threadIdx.x;
  out[i] = bf2f(ab[i]) / cs[i >> 12];
}

extern "C" void kernel_launch(void* const* d_in, const int* in_sizes, int n_in,
                              void* d_out, int out_size, void* d_ws, size_t ws_size,
                              hipStream_t stream) {
  const float* x       = (const float*)d_in[0];
  const float* tinit   = (const float*)d_in[1];
  const float* Wq      = (const float*)d_in[2];
  const float* Wk      = (const float*)d_in[3];
  const float* Wv      = (const float*)d_in[4];
  const float* ln_in_g = (const float*)d_in[5];
  const float* ln_in_b = (const float*)d_in[6];
  const float* ln_t_g  = (const float*)d_in[7];
  const float* ln_t_b  = (const float*)d_in[8];
  const float* ln_m_g  = (const float*)d_in[9];
  const float* ln_m_b  = (const float*)d_in[10];
  const float* W1      = (const float*)d_in[11];
  const float* b1      = (const float*)d_in[12];
  const float* W2      = (const float*)d_in[13];
  const float* b2      = (const float*)d_in[14];
  (void)in_sizes; (void)n_in; (void)out_size; (void)ws_size;

  // ---- workspace (~89.3 MiB peak) ----
  char* ws = (char*)d_ws;
  size_t off = 0;
  auto alloc = [&](size_t bytes) {
    void* p = ws + off;
    off += (bytes + 255) & ~(size_t)255;
    return p;
  };
  float* meanp   = (float*)alloc(32768ULL * 4);
  float* rstdp   = (float*)alloc(32768ULL * 4);
  float* ps      = (float*)alloc(262144ULL * 4);   // 8x32768 partial sums
  float* ps2     = (float*)alloc(262144ULL * 4);
  u16* xn        = (u16*)alloc(16777216ULL * 2);   // [4,4096,1024] bf16, 32 MB
  u16* vT        = (u16*)alloc(16777216ULL * 2);   // [4,1024,4096] bf16, 32 MB
  u16* attnbf    = (u16*)alloc(4194304ULL * 2);    // [4*256,4096] bf16, 8 MB
  u16* tln       = (u16*)alloc(1048576ULL * 2);    // tln / mfeat (aliased)
  u16* qk        = (u16*)alloc(1048576ULL * 2);
  u16* hidden    = (u16*)alloc(524288ULL * 2);
  float* tmpl    = (float*)alloc(1048576ULL * 4);  // [4*256,1024] fp32
  u16* WqkT      = (u16*)alloc(1048576ULL * 2);    // scale*Wk*Wq^T
  u16* WvT       = (u16*)alloc(1048576ULL * 2);
  u16* W1T       = (u16*)alloc(524288ULL * 2);
  u16* W2T       = (u16*)alloc(524288ULL * 2);
  float* colsum  = (float*)alloc(1024ULL * 4);

  // temp bf16 weight casts live in attnbf slab (dead until first softmax)
  u16* Wkbf = attnbf;
  u16* Wqbf = attnbf + 1048576;

  float* outT        = (float*)d_out;               // [B,D,N]
  float* attnOutBase = (float*)d_out + 2097152;     // [B,N,L] fp32 final
  float* logitsS     = attnOutBase + 4194304;       // 16.8 MB fp32 scratch

  dim3 blk(256);

  ln_part<<<dim3(4096), blk, 0, stream>>>(x, ps, ps2);
  ln_red<<<dim3(128), blk, 0, stream>>>(ps, ps2, meanp, rstdp);

  // weight prep (once)
  castbf<<<dim3(4096), blk, 0, stream>>>(Wk, Wkbf);
  castbf<<<dim3(4096), blk, 0, stream>>>(Wq, Wqbf);
  mgemm<E_SCALEBF><<<dim3(8, 8, 1), blk, 0, stream>>>(
      Wkbf, Wqbf, WqkT, 1024, 1024, 1024, 1024, 0, 0, 0, nullptr, nullptr);
  tcast<<<dim3(32, 32), blk, 0, stream>>>(Wv, WvT, 1024, 1024);
  tcast<<<dim3(16, 32), blk, 0, stream>>>(W1, W1T, 1024, 512);
  tcast<<<dim3(32, 16), blk, 0, stream>>>(W2, W2T, 512, 1024);

  for (int g = 0; g < 2; ++g) {
    const float* xg = x + (long)g * 16777216;
    float* mg = meanp + g * 16384;
    float* rg = rstdp + g * 16384;

    xn_make<<<dim3(128, 32, 4), blk, 0, stream>>>(xg, xn, mg, rg, ln_in_g, ln_in_b);
    // vT[z][d][l] = sum_c WvT[d][c] * xn[z][l][c]
    mgemm<E_BF16><<<dim3(32, 8, 4), blk, 0, stream>>>(
        WvT, xn, vT, 1024, 1024, 1024, 4096, 0, 4194304L, 4194304L, nullptr, nullptr);
    bcast_tmpl<<<dim3(4096), blk, 0, stream>>>(tinit, tmpl);

    for (int it = 0; it < 6; ++it) {
      row_ln_bf<<<dim3(1024), blk, 0, stream>>>(tmpl, tln, ln_t_g, ln_t_b);
      // qk[row][c] = sum_dt tln[row][dt] * WqkT[c][dt]
      mgemm<E_BF16><<<dim3(8, 8, 1), blk, 0, stream>>>(
          tln, WqkT, qk, 1024, 1024, 1024, 1024, 0, 0, 0, nullptr, nullptr);
      // logits[z][n][l] = sum_c qk[z*256+n][c] * xn[z][l][c]  (fp32 out)
      mgemm<E_F32><<<dim3(32, 2, 4), blk, 0, stream>>>(
          qk, xn, logitsS, 1024, 1024, 1024, 4096, 262144L, 4194304L, 1048576L,
          nullptr, nullptr);
      softmax_tile<<<dim3(128, 4), blk, 0, stream>>>(logitsS, attnbf);
      row_sum_bf<<<dim3(1024), blk, 0, stream>>>(attnbf, colsum);
      // tmpl[z*256+n][d] += (sum_l attn[n][l]*vT[z][d][l]) / colsum  (split-K=2)
      mgemm<E_UPD, 2><<<dim3(8, 2, 8), blk, 0, stream>>>(
          attnbf, vT, tmpl, 4096, 4096, 4096, 1024, 1048576L, 4194304L, 262144L,
          nullptr, colsum);
      row_ln_bf<<<dim3(1024), blk, 0, stream>>>(tmpl, tln, ln_m_g, ln_m_b);
      // hidden = relu(mfeat @ W1 + b1)
      mgemm<E_RELU><<<dim3(4, 8, 1), blk, 0, stream>>>(
          tln, W1T, hidden, 1024, 1024, 1024, 512, 0, 0, 0, b1, nullptr);
      // tmpl += hidden @ W2 + b2
      mgemm<E_ADDB><<<dim3(8, 8, 1), blk, 0, stream>>>(
          hidden, W2T, tmpl, 512, 512, 512, 1024, 0, 0, 0, b2, nullptr);
    }

    attn_final_g<<<dim3(16384), blk, 0, stream>>>(attnbf, colsum,
                                                  attnOutBase + (long)g * 4194304);
    transpose_f32<<<dim3(32, 8, 4), blk, 0, stream>>>(
        tmpl, outT + (long)g * 1048576, 256, 1024, 262144L, 262144L);
  }
}